// Round 1
// baseline (762.409 us; speedup 1.0000x reference)
//
#include <hip/hip_runtime.h>
#include <math.h>

#define LSEQ 4
#define NNODES 50000
#define EMB 128
#define NH 4
#define HD 32
#define RREL 16
#define HID 64
#define LBL 32
#define NEDGE 625000

// ---------------- weight prep: transpose/concat into GEMM-friendly B (K x N, row-major) ----
// Bqkv: 128x384   Bqkv[k*384+o] = in_proj_w[o*128+k]
// Bout: 128x128   Bout[k*128+o] = out_proj_w[o*128+k]
// B1:   128x1088  col<64: root1[k*64+c]; else r=(c-64)/64, o=(c-64)%64 -> w1[r][k][o]
// B2:   64x576    col<32: root2[k*32+c]; col in [32,544): r=(c-32)/32, o=(c-32)%32 -> w2[r][k][o]; col>=544: 0
__global__ __launch_bounds__(256) void prep_weights(
    const float* __restrict__ ipw, const float* __restrict__ opw,
    const float* __restrict__ w1, const float* __restrict__ root1,
    const float* __restrict__ w2, const float* __restrict__ root2,
    float* __restrict__ Bqkv, float* __restrict__ Bout,
    float* __restrict__ B1, float* __restrict__ B2) {
  int i = blockIdx.x * 256 + threadIdx.x;
  if (i < 49152) {
    int k = i / 384, o = i % 384;
    Bqkv[i] = ipw[o * 128 + k];
  } else if (i < 65536) {
    int j = i - 49152; int k = j / 128, o = j % 128;
    Bout[j] = opw[o * 128 + k];
  } else if (i < 204800) {
    int j = i - 65536; int k = j / 1088, c = j % 1088;
    B1[j] = (c < 64) ? root1[k * 64 + c]
                     : w1[((c - 64) / 64) * (128 * 64) + k * 64 + ((c - 64) % 64)];
  } else if (i < 241664) {
    int j = i - 204800; int k = j / 576, c = j % 576;
    float v = 0.f;
    if (c < 32) v = root2[k * 32 + c];
    else if (c < 544) v = w2[((c - 32) / 32) * (64 * 32) + k * 32 + ((c - 32) % 32)];
    B2[j] = v;
  }
}

// ---------------- f32 GEMM: C[M,N] = A[M,K] @ B[K,N] (+bias[N]) ------------------
// BM=128, BN=64, BK=16, 256 threads, per-thread 8x4. N%64==0, K%16==0 assumed; M guarded.
__global__ __launch_bounds__(256) void gemm128(
    const float* __restrict__ A, const float* __restrict__ B,
    float* __restrict__ C, const float* __restrict__ bias,
    int M, int N, int K, int lda, int ldb, int ldc) {
  __shared__ __align__(16) float As[16][132];
  __shared__ __align__(16) float Bs[16][64];
  int t = threadIdx.x;
  int row0 = blockIdx.x * 128;
  int col0 = blockIdx.y * 64;
  int ty = t >> 4, tx = t & 15;
  float acc[8][4];
#pragma unroll
  for (int i = 0; i < 8; i++)
#pragma unroll
    for (int j = 0; j < 4; j++) acc[i][j] = 0.f;

  for (int k0 = 0; k0 < K; k0 += 16) {
#pragma unroll
    for (int q = 0; q < 2; q++) {
      int f = t * 2 + q;          // 0..511 float4 id
      int ar = f >> 2;            // 0..127
      int ac = (f & 3) * 4;       // 0,4,8,12
      int gm = row0 + ar;
      float4 v = make_float4(0.f, 0.f, 0.f, 0.f);
      if (gm < M) v = *(const float4*)&A[(size_t)gm * lda + k0 + ac];
      As[ac + 0][ar] = v.x; As[ac + 1][ar] = v.y;
      As[ac + 2][ar] = v.z; As[ac + 3][ar] = v.w;
    }
    {
      int br = t >> 4;            // 0..15
      int bc = (t & 15) * 4;      // 0..60
      float4 v = *(const float4*)&B[(size_t)(k0 + br) * ldb + col0 + bc];
      *(float4*)&Bs[br][bc] = v;
    }
    __syncthreads();
#pragma unroll
    for (int k = 0; k < 16; k++) {
      float4 a0 = *(const float4*)&As[k][ty * 8];
      float4 a1 = *(const float4*)&As[k][ty * 8 + 4];
      float4 b0 = *(const float4*)&Bs[k][tx * 4];
      float a[8] = {a0.x, a0.y, a0.z, a0.w, a1.x, a1.y, a1.z, a1.w};
      float b[4] = {b0.x, b0.y, b0.z, b0.w};
#pragma unroll
      for (int i = 0; i < 8; i++)
#pragma unroll
        for (int j = 0; j < 4; j++) acc[i][j] = fmaf(a[i], b[j], acc[i][j]);
    }
    __syncthreads();
  }
  float bv[4] = {0.f, 0.f, 0.f, 0.f};
  if (bias) {
    float4 b4 = *(const float4*)&bias[col0 + tx * 4];
    bv[0] = b4.x; bv[1] = b4.y; bv[2] = b4.z; bv[3] = b4.w;
  }
#pragma unroll
  for (int i = 0; i < 8; i++) {
    int gm = row0 + ty * 8 + i;
    if (gm < M) {
      float4 o;
      o.x = acc[i][0] + bv[0]; o.y = acc[i][1] + bv[1];
      o.z = acc[i][2] + bv[2]; o.w = acc[i][3] + bv[3];
      *(float4*)&C[(size_t)gm * ldc + col0 + tx * 4] = o;
    }
  }
}

// ---------------- attention (only l=0 row of output needed) ----------------------
// kv layout: kv[(m*NNODES+n)*256 + c]; c<128 -> k channel c, c>=128 -> v channel c-128
__global__ __launch_bounds__(256) void attn_kernel(
    const float* __restrict__ q0, const float* __restrict__ kv,
    float* __restrict__ o0) {
  int t = threadIdx.x;
  int g = t >> 5;
  int lane = t & 31;
  int gid = blockIdx.x * 8 + g;   // (n,h) pair id, exact coverage
  int n = gid >> 2;
  int h = gid & 3;
  int ch = h * 32 + lane;
  float q = q0[(size_t)n * 128 + ch];
  float s[4];
#pragma unroll
  for (int m = 0; m < 4; m++) {
    float kk = kv[((size_t)(m * NNODES + n)) * 256 + ch];
    float p = q * kk;
#pragma unroll
    for (int off = 16; off; off >>= 1) p += __shfl_xor(p, off, 32);
    s[m] = p * 0.17677669529663687f;  // 1/sqrt(32)
  }
  float mx = fmaxf(fmaxf(s[0], s[1]), fmaxf(s[2], s[3]));
  float e[4], sum = 0.f;
#pragma unroll
  for (int m = 0; m < 4; m++) { e[m] = __expf(s[m] - mx); sum += e[m]; }
  float inv = 1.0f / sum;
  float out = 0.f;
#pragma unroll
  for (int m = 0; m < 4; m++)
    out += e[m] * inv * kv[((size_t)(m * NNODES + n)) * 256 + 128 + ch];
  o0[(size_t)n * 128 + ch] = out;
}

// ---------------- edge count ------------------------------------------------------
__global__ __launch_bounds__(256) void count_edges(
    const int* __restrict__ dst, const int* __restrict__ et, int* __restrict__ cnt) {
  int e = blockIdx.x * 256 + threadIdx.x;
  if (e < NEDGE) atomicAdd(&cnt[et[e] * NNODES + dst[e]], 1);
}

// ---------------- layer1: init (root+bias), edge aggregate, relu -----------------
__global__ __launch_bounds__(256) void init1(
    const float* __restrict__ Y1, const float* __restrict__ b1, float* __restrict__ x1) {
  int i = blockIdx.x * 256 + threadIdx.x;   // i < NNODES*64 exact
  int n = i >> 6, j = i & 63;
  x1[i] = Y1[(size_t)n * 1088 + j] + b1[j];
}

__global__ __launch_bounds__(256) void agg1(
    const int* __restrict__ src, const int* __restrict__ dst, const int* __restrict__ et,
    const int* __restrict__ cnt, const float* __restrict__ Y1, float* __restrict__ x1) {
  int t = blockIdx.x * 256 + threadIdx.x;
  int e = t >> 6, j = t & 63;               // exact coverage NEDGE*64
  int s = src[e], d = dst[e], r = et[e];
  float scale = 1.0f / (float)cnt[r * NNODES + d];
  float v = Y1[(size_t)s * 1088 + 64 + r * 64 + j] * scale;
  atomicAdd(&x1[d * 64 + j], v);
}

__global__ __launch_bounds__(256) void relu1(float* __restrict__ x1) {
  int i = blockIdx.x * 256 + threadIdx.x;
  x1[i] = fmaxf(x1[i], 0.f);
}

// ---------------- layer2: init, aggregate, softmax -------------------------------
__global__ __launch_bounds__(256) void init2(
    const float* __restrict__ Y2, const float* __restrict__ b2, float* __restrict__ a2) {
  int i = blockIdx.x * 256 + threadIdx.x;   // i < NNODES*32 exact
  int n = i >> 5, j = i & 31;
  a2[i] = Y2[(size_t)n * 576 + j] + b2[j];
}

__global__ __launch_bounds__(256) void agg2(
    const int* __restrict__ src, const int* __restrict__ dst, const int* __restrict__ et,
    const int* __restrict__ cnt, const float* __restrict__ Y2, float* __restrict__ a2) {
  int t = blockIdx.x * 256 + threadIdx.x;
  int e = t >> 5, j = t & 31;               // exact coverage NEDGE*32
  int s = src[e], d = dst[e], r = et[e];
  float scale = 1.0f / (float)cnt[r * NNODES + d];
  float v = Y2[(size_t)s * 576 + 32 + r * 32 + j] * scale;
  atomicAdd(&a2[d * 32 + j], v);
}

__global__ __launch_bounds__(256) void softmax_out(
    const float* __restrict__ a2, float* __restrict__ out) {
  int t = blockIdx.x * 256 + threadIdx.x;   // NNODES*32 exact
  int n = t >> 5, lane = t & 31;
  float v = a2[(size_t)n * 32 + lane];
  float mx = v;
#pragma unroll
  for (int off = 16; off; off >>= 1) mx = fmaxf(mx, __shfl_xor(mx, off, 32));
  float e = __expf(v - mx);
  float sum = e;
#pragma unroll
  for (int off = 16; off; off >>= 1) sum += __shfl_xor(sum, off, 32);
  out[(size_t)n * 32 + lane] = e / sum;
}

// =================================================================================
extern "C" void kernel_launch(void* const* d_in, const int* in_sizes, int n_in,
                              void* d_out, int out_size, void* d_ws, size_t ws_size,
                              hipStream_t stream) {
  const float* emb   = (const float*)d_in[0];
  const float* ipw   = (const float*)d_in[1];
  const float* ipb   = (const float*)d_in[2];
  const float* opw   = (const float*)d_in[3];
  const float* opb   = (const float*)d_in[4];
  const float* w1    = (const float*)d_in[5];
  const float* root1 = (const float*)d_in[6];
  const float* b1    = (const float*)d_in[7];
  const float* w2    = (const float*)d_in[8];
  const float* root2 = (const float*)d_in[9];
  const float* b2    = (const float*)d_in[10];
  const int*   eidx  = (const int*)d_in[11];
  const int*   etype = (const int*)d_in[12];
  const int* srcp = eidx;
  const int* dstp = eidx + NEDGE;

  float* ws = (float*)d_ws;
  size_t off = 0;
  auto alloc = [&](size_t nf) { float* p = ws + off; off += (nf + 63) & ~(size_t)63; return p; };

  // R1 region reused: [kv (51.2M) | q0 (6.4M)] -> Y1 (54.4M) -> Y2 (28.8M)
  float* R1   = alloc(57600000);
  float* kv   = R1;
  float* q0   = R1 + 51200000;
  float* Y1   = R1;
  float* Y2   = R1;
  float* o0   = alloc(6400000);
  float* x0   = alloc(6400000);
  float* x1   = alloc(3200000);
  float* a2   = alloc(1600000);
  int*   cnt  = (int*)alloc(800000);
  float* Bqkv = alloc(49152);
  float* Bout = alloc(16384);
  float* B1   = alloc(139264);
  float* B2   = alloc(36864);

  // 1) weight prep
  prep_weights<<<dim3((241664 + 255) / 256), dim3(256), 0, stream>>>(
      ipw, opw, w1, root1, w2, root2, Bqkv, Bout, B1, B2);

  // 2) KV projection: (200000 x 128) @ (128 x 256) -> kv
  gemm128<<<dim3((200000 + 127) / 128, 4), dim3(256), 0, stream>>>(
      emb, Bqkv + 128, kv, ipb + 128, 200000, 256, 128, 128, 384, 256);

  // 3) Q projection at l=0: (50000 x 128) @ (128 x 128) -> q0
  gemm128<<<dim3((50000 + 127) / 128, 2), dim3(256), 0, stream>>>(
      emb, Bqkv, q0, ipb, 50000, 128, 128, 128, 384, 128);

  // 4) attention -> o0
  attn_kernel<<<dim3(25000), dim3(256), 0, stream>>>(q0, kv, o0);

  // 5) out_proj: (50000 x 128) @ (128 x 128) -> x0
  gemm128<<<dim3(391, 2), dim3(256), 0, stream>>>(
      o0, Bout, x0, opb, 50000, 128, 128, 128, 128, 128);

  // 6) Y1 = x0 @ [root1 | W1_r]: (50000 x 128) @ (128 x 1088)
  gemm128<<<dim3(391, 17), dim3(256), 0, stream>>>(
      x0, B1, Y1, nullptr, 50000, 1088, 128, 128, 1088, 1088);

  // 7) edge counts
  hipMemsetAsync(cnt, 0, (size_t)RREL * NNODES * sizeof(int), stream);
  count_edges<<<dim3((NEDGE + 255) / 256), dim3(256), 0, stream>>>(dstp, etype, cnt);

  // 8) layer1: init + aggregate + relu
  init1<<<dim3(NNODES * 64 / 256), dim3(256), 0, stream>>>(Y1, b1, x1);
  agg1<<<dim3(NEDGE * 64 / 256), dim3(256), 0, stream>>>(srcp, dstp, etype, cnt, Y1, x1);
  relu1<<<dim3(NNODES * 64 / 256), dim3(256), 0, stream>>>(x1);

  // 9) Y2 = x1 @ [root2 | W2_r | pad]: (50000 x 64) @ (64 x 576)
  gemm128<<<dim3(391, 9), dim3(256), 0, stream>>>(
      x1, B2, Y2, nullptr, 50000, 576, 64, 64, 576, 576);

  // 10) layer2: init + aggregate + softmax
  init2<<<dim3(NNODES * 32 / 256), dim3(256), 0, stream>>>(Y2, b2, a2);
  agg2<<<dim3(NEDGE * 32 / 256), dim3(256), 0, stream>>>(srcp, dstp, etype, cnt, Y2, a2);
  softmax_out<<<dim3(NNODES * 32 / 256), dim3(256), 0, stream>>>(a2, (float*)d_out);
}